// Round 4
// baseline (279.695 us; speedup 1.0000x reference)
//
#include <hip/hip_runtime.h>
#include <hip/hip_bf16.h>
#include <cstdint>

// Problem constants: b=2, dim=192, heads=6, ch=32, h=w=48, n=2304
#define NSP   2304
#define NT    144            // 2304/16 n-tiles
#define ATTN_ELEMS 63700992  // 2*6*2304*2304

typedef __attribute__((ext_vector_type(8))) __bf16 bf16x8;   // MFMA A/B frag (4 VGPRs)
typedef __attribute__((ext_vector_type(4))) float  float4v;  // MFMA C/D frag

// round-to-nearest-even float -> bf16 bits
__device__ __forceinline__ unsigned short f2bf(float f) {
  union { float f; unsigned int u; } v; v.f = f;
  unsigned int u = v.u;
  unsigned int r = u + 0x7FFFu + ((u >> 16) & 1u);
  return (unsigned short)(r >> 16);
}

__device__ __forceinline__ float bf2f(unsigned int bits16) {
  union { unsigned int u; float f; } v; v.u = bits16 << 16; return v.f;
}

// ---------------------------------------------------------------------------
// Kernel 1: pack weights (M=576 = [wq;wk;wv]) and x into MFMA fragment layouts
//   A-frag layout: elem jj of lane -> [m = lane&15][k = (lane>>4)*8 + jj]
//   B-frag layout: elem jj of lane -> [k = (lane>>4)*8 + jj][n = lane&15]
// Wp: [36 mtiles][6 kchunks][64 lanes][8]   Xp: [b][144 ntiles][6 kchunks][64][8]
// Also zeroes the 768-entry row-sum buffer (runs strictly before proj).
// ---------------------------------------------------------------------------
__global__ __launch_bounds__(256) void prep_pack(
    const float* __restrict__ wq, const float* __restrict__ wk,
    const float* __restrict__ wv, const float* __restrict__ x,
    unsigned short* __restrict__ Wp, unsigned short* __restrict__ Xp,
    float* __restrict__ sums)
{
  int t = blockIdx.x * 256 + threadIdx.x;      // 486*256 = 124416 = 1944 groups
  if (t < 768) sums[t] = 0.f;                  // zero q/k row-sum accumulators
  int lane = t & 63;
  int g = t >> 6;
  int quad = lane >> 4, col = lane & 15;
  union { int4 v; unsigned short u[8]; } o;
  if (g < 216) {                               // W: 36*6 groups
    int mt = g / 6, kc = g % 6;
    int oo = mt * 16 + col;
    int c0 = kc * 32 + quad * 8;
    const float* w = (oo < 192) ? (wq + (size_t)oo * 192)
                   : (oo < 384) ? (wk + (size_t)(oo - 192) * 192)
                                : (wv + (size_t)(oo - 384) * 192);
#pragma unroll
    for (int jj = 0; jj < 8; ++jj) o.u[jj] = f2bf(w[c0 + jj]);
    ((int4*)Wp)[(size_t)g * 64 + lane] = o.v;
  } else {                                     // X: 2*144*6 groups
    int gx = g - 216;
    int kc = gx % 6;
    int bnt = gx / 6;                          // b*144 + nt
    int b = bnt / 144;
    int n = (bnt % 144) * 16 + col;
    int c0 = kc * 32 + quad * 8;
    const float* xp = x + ((size_t)b * 192 + c0) * NSP + n;
#pragma unroll
    for (int jj = 0; jj < 8; ++jj) o.u[jj] = f2bf(xp[(size_t)jj * NSP]);
    ((int4*)Xp)[(size_t)gx * 64 + lane] = o.v;
  }
}

// ---------------------------------------------------------------------------
// Kernel 2: MFMA projection GEMM: out[o,n] = sum_c Wall[o,c] x[b,c,n]
//   M=576 (3 weights), K=192 (6 chunks of 32), N=2304. Per wave: 16x64 tile.
//   o<192 -> q (ws), <384 -> k (ws), else v (directly to d_out region 1).
// FUSED rownorm: each q/k wave reduces its 16 rows' sum-of-squares over its
// 64 n-columns in-register (in-quad shfl butterfly) and atomicAdds one f32
// per row (36 adds/row total). Saves the separate rownorm kernel + 7MB read.
// ---------------------------------------------------------------------------
__global__ __launch_bounds__(256) void proj_mfma(
    const bf16x8* __restrict__ Wp, const bf16x8* __restrict__ Xp,
    float* __restrict__ qws, float* __restrict__ kws, float* __restrict__ vout,
    float* __restrict__ sums)
{
  int lane = threadIdx.x & 63, w = threadIdx.x >> 6;
  int ng = blockIdx.x * 4 + w;                 // 0..35 (groups of 4 ntiles)
  int mt = blockIdx.y;                         // 0..35
  int b  = blockIdx.z;                         // 0..1
  int nt0 = ng * 4;
  float4v acc0 = {0.f,0.f,0.f,0.f};
  float4v acc1 = acc0, acc2 = acc0, acc3 = acc0;
#pragma unroll
  for (int kc = 0; kc < 6; ++kc) {
    bf16x8 a = Wp[(size_t)(mt * 6 + kc) * 64 + lane];
    const bf16x8* xb = Xp + (size_t)((b * 144 + nt0) * 6 + kc) * 64 + lane;
    acc0 = __builtin_amdgcn_mfma_f32_16x16x32_bf16(a, xb[0],    acc0, 0, 0, 0);
    acc1 = __builtin_amdgcn_mfma_f32_16x16x32_bf16(a, xb[384],  acc1, 0, 0, 0);
    acc2 = __builtin_amdgcn_mfma_f32_16x16x32_bf16(a, xb[768],  acc2, 0, 0, 0);
    acc3 = __builtin_amdgcn_mfma_f32_16x16x32_bf16(a, xb[1152], acc3, 0, 0, 0);
  }
  int quad = lane >> 4, col = lane & 15;
  int o0 = mt * 16 + quad * 4;                 // C/D layout: row = quad*4+reg
  float* dst;
  if (mt < 12)      dst = qws + ((size_t)b * 192 + o0) * NSP;
  else if (mt < 24) dst = kws + ((size_t)b * 192 + (o0 - 192)) * NSP;
  else              dst = vout + ((size_t)b * 192 + (o0 - 384)) * NSP;
  float4v acc[4] = {acc0, acc1, acc2, acc3};
#pragma unroll
  for (int tt = 0; tt < 4; ++tt)
#pragma unroll
    for (int r = 0; r < 4; ++r)
      dst[(size_t)r * NSP + (nt0 + tt) * 16 + col] = acc[tt][r];

  // fused row-sum-of-squares for q,k (norm is over n, rows are (b,o))
  if (mt < 24) {
    int rbase = (mt < 12) ? (b * 192 + o0) : (384 + b * 192 + (o0 - 192));
#pragma unroll
    for (int r = 0; r < 4; ++r) {
      float p = acc0[r]*acc0[r] + acc1[r]*acc1[r]
              + acc2[r]*acc2[r] + acc3[r]*acc3[r];
#pragma unroll
      for (int off = 1; off < 16; off <<= 1) p += __shfl_xor(p, off);
      if (col == 0) atomicAdd(&sums[rbase + r], p);
    }
  }
}

// ---------------------------------------------------------------------------
// Kernel 3: normalize q,k and pack into attention fragment layout (bf16):
//   P[((bh*144 + jt)*64 + lane)*8 + jj] = src[b][h*32 + (lane>>4)*8+jj][jt*16 + (lane&15)] * inv
// inv computed on the fly from the atomically-accumulated sums.
// One block = 32ch x 64n tile, LDS transpose, 16B coalesced stores.
// ---------------------------------------------------------------------------
__global__ __launch_bounds__(256) void packqk(
    const float* __restrict__ qws, const float* __restrict__ kws,
    const float* __restrict__ sums,
    unsigned short* __restrict__ Qp, unsigned short* __restrict__ Kp)
{
  int which = blockIdx.z;                      // 0=q, 1=k
  int bh = blockIdx.y;                         // 0..11
  int nc = blockIdx.x;                         // 0..35 (64-wide n chunks)
  const float* src = which ? kws : qws;
  int b = bh / 6, h = bh % 6;
  __shared__ float xs[32][65];
  __shared__ float ivs[32];
  int t = threadIdx.x;
  if (t < 32) {
    float sm = sums[which * 384 + b * 192 + h * 32 + t];
    ivs[t] = 1.0f / fmaxf(sqrtf(sm), 1e-12f);
  }
  __syncthreads();
  const float* base = src + ((size_t)b * 192 + h * 32) * NSP + nc * 64;
#pragma unroll
  for (int i = 0; i < 8; ++i) {
    int idx = t + 256 * i;                     // 2048 = 32x64
    int ch = idx >> 6, nl = idx & 63;
    xs[ch][nl] = base[(size_t)ch * NSP + nl] * ivs[ch];
  }
  __syncthreads();
  int jl = t >> 6, lane = t & 63, quad = lane >> 4, col = lane & 15;
  int jt = nc * 4 + jl;
  union { int4 v; unsigned short u[8]; } o;
#pragma unroll
  for (int jj = 0; jj < 8; ++jj) o.u[jj] = f2bf(xs[quad * 8 + jj][jl * 16 + col]);
  int4* dst = (int4*)(which ? Kp : Qp);
  dst[(size_t)(bh * 144 + jt) * 64 + lane] = o.v;
}

// ---------------------------------------------------------------------------
// Kernel 4: attention. Block = one (bh, itile=16 n-rows), 512 threads = 8
// waves. Wave w owns jt = w + 8u (u=0..17), INTERLEAVED so that 2 consecutive
// u across all 8 waves tile 256 contiguous output columns.
//
// acc = mfma(Q_tile, K_tile): lane(quad,col) reg r holds
//     S[n = itile*16 + col][m = jt*16 + quad*4 + r]
// exp(S*T) cached as packed bf16 in registers.
// Pass 2 routes through an LDS transpose so every global store instruction is
// a fully contiguous, 128B-aligned 1KB wave store (complete cache lines).
// ---------------------------------------------------------------------------
__global__ __launch_bounds__(512) void attn_kernel(
    const bf16x8* __restrict__ Qp, const bf16x8* __restrict__ Kp,
    const float* __restrict__ temp, float* __restrict__ out)
{
  int lane = threadIdx.x & 63, w = threadIdx.x >> 6;   // 8 waves
  int itile = blockIdx.x;                      // 0..143
  int bh = blockIdx.y;                         // 0..11
  float T = temp[bh % 6];
  // K tile for this block's 16 n-rows: used as B operand (fixed all iters)
  bf16x8 kf = Kp[((size_t)bh * NT + itile) * 64 + lane];
  const bf16x8* qb = Qp + (size_t)bh * NT * 64 + lane;

  unsigned int ec[36];                         // 18 jt x 4 exps packed bf16
  float s = 0.f;
#pragma unroll
  for (int u = 0; u < 18; ++u) {
    int jt = w + 8 * u;                        // interleaved assignment
    bf16x8 qf = qb[(size_t)jt * 64];
    float4v acc = {0.f,0.f,0.f,0.f};
    acc = __builtin_amdgcn_mfma_f32_16x16x32_bf16(qf, kf, acc, 0, 0, 0);
    float e0 = __expf(acc[0] * T);
    float e1 = __expf(acc[1] * T);
    float e2 = __expf(acc[2] * T);
    float e3 = __expf(acc[3] * T);
    s += (e0 + e1) + (e2 + e3);
    ec[2*u]   = (unsigned int)f2bf(e0) | ((unsigned int)f2bf(e1) << 16);
    ec[2*u+1] = (unsigned int)f2bf(e2) | ((unsigned int)f2bf(e3) << 16);
  }
  // per-lane s covers this wave's 18 jt, its quad's 4 m, for n=col.
  // reduce across the 4 quads (lanes col, col+16, col+32, col+48):
  s += __shfl_xor(s, 16);
  s += __shfl_xor(s, 32);
  __shared__ float ls[8][16];
  if (lane < 16) ls[w][lane] = s;
  __syncthreads();
  int col = lane & 15, quad = lane >> 4;
  float tot = 0.f;
#pragma unroll
  for (int ww = 0; ww < 8; ++ww) tot += ls[ww][col];
  float inv = 1.0f / tot;

  // pass 2: 9 chunks of 256 columns. Each chunk: scale 8 vals/thread into a
  // [16 rows][260] padded LDS tile (write banks evenly spread, reads linear),
  // then each wave streams 2 complete rows as contiguous 1KB dwordx4 stores.
  __shared__ float xs[16][260];                // 16.6 KB, +4 pad keeps 16B align
  float* obase = out + (size_t)bh * NSP * NSP + (size_t)(itile * 16) * NSP;
  for (int c = 0; c < 9; ++c) {
#pragma unroll
    for (int ul = 0; ul < 2; ++ul) {
      int u = 2 * c + ul;                      // jt = w + 8u -> chunk-local col
      unsigned int p0 = ec[2*u], p1 = ec[2*u+1];
      float4v o4;
      o4[0] = bf2f(p0 & 0xffffu) * inv;
      o4[1] = bf2f(p0 >> 16)     * inv;
      o4[2] = bf2f(p1 & 0xffffu) * inv;
      o4[3] = bf2f(p1 >> 16)     * inv;
      *(float4v*)&xs[col][(ul * 8 + w) * 16 + quad * 4] = o4;
    }
    __syncthreads();
#pragma unroll
    for (int rr = 0; rr < 2; ++rr) {
      int row = w + rr * 8;
      float4v o4 = *(const float4v*)&xs[row][lane * 4];
      *(float4v*)(obase + (size_t)row * NSP + c * 256 + lane * 4) = o4;
    }
    __syncthreads();
  }
}

extern "C" void kernel_launch(void* const* d_in, const int* in_sizes, int n_in,
                              void* d_out, int out_size, void* d_ws, size_t ws_size,
                              hipStream_t stream) {
  const float* x    = (const float*)d_in[0];   // [2][192][2304]
  const float* wq   = (const float*)d_in[1];   // [192][192]
  const float* wk   = (const float*)d_in[2];
  const float* wv   = (const float*)d_in[3];
  const float* temp = (const float*)d_in[4];   // [6]

  float* attn_out = (float*)d_out;                     // [2][6][2304][2304]
  float* vout     = attn_out + (size_t)ATTN_ELEMS;     // [2][6][32][2304]

  // workspace carve-up (~12.6 MB total, all 16B-aligned)
  float* qws = (float*)d_ws;                   // 884736 f32
  float* kws = qws + 884736;                   // 884736 f32
  float* sums = kws + 884736;                  // 768 f32 (atomic accumulators)
  unsigned short* Wp = (unsigned short*)(sums + 768);  // 110592 bf16
  unsigned short* Xp = Wp + 110592;                    // 884736 bf16
  unsigned short* Qp = Xp + 884736;                    // 884736 bf16
  unsigned short* Kp = Qp + 884736;                    // 884736 bf16

  hipLaunchKernelGGL(prep_pack, dim3(486), dim3(256), 0, stream,
                     wq, wk, wv, x, Wp, Xp, sums);
  hipLaunchKernelGGL(proj_mfma, dim3(9, 36, 2), dim3(256), 0, stream,
                     (const bf16x8*)Wp, (const bf16x8*)Xp, qws, kws, vout, sums);
  hipLaunchKernelGGL(packqk, dim3(36, 12, 2), dim3(256), 0, stream,
                     qws, kws, sums, Qp, Kp);
  hipLaunchKernelGGL(attn_kernel, dim3(144, 12), dim3(512), 0, stream,
                     (const bf16x8*)Qp, (const bf16x8*)Kp, temp, attn_out);
}

// Round 5
// 274.943 us; speedup vs baseline: 1.0173x; 1.0173x over previous
//
#include <hip/hip_runtime.h>
#include <hip/hip_bf16.h>
#include <cstdint>

// Problem constants: b=2, dim=192, heads=6, ch=32, h=w=48, n=2304
#define NSP   2304
#define NT    144            // 2304/16 n-tiles
#define ATTN_ELEMS 63700992  // 2*6*2304*2304

typedef __attribute__((ext_vector_type(8))) __bf16 bf16x8;   // MFMA A/B frag (4 VGPRs)
typedef __attribute__((ext_vector_type(4))) float  float4v;  // MFMA C/D frag

// round-to-nearest-even float -> bf16 bits
__device__ __forceinline__ unsigned short f2bf(float f) {
  union { float f; unsigned int u; } v; v.f = f;
  unsigned int u = v.u;
  unsigned int r = u + 0x7FFFu + ((u >> 16) & 1u);
  return (unsigned short)(r >> 16);
}

__device__ __forceinline__ float bf2f(unsigned int bits16) {
  union { unsigned int u; float f; } v; v.u = bits16 << 16; return v.f;
}

// ---------------------------------------------------------------------------
// Kernel 1: pack weights (M=576 = [wq;wk;wv]) and x into MFMA fragment layouts
//   A-frag layout: elem jj of lane -> [m = lane&15][k = (lane>>4)*8 + jj]
//   B-frag layout: elem jj of lane -> [k = (lane>>4)*8 + jj][n = lane&15]
// Wp: [36 mtiles][6 kchunks][64 lanes][8]   Xp: [b][144 ntiles][6 kchunks][64][8]
// Also zeroes the 768-entry row-sum buffer (runs strictly before proj).
// ---------------------------------------------------------------------------
__global__ __launch_bounds__(256) void prep_pack(
    const float* __restrict__ wq, const float* __restrict__ wk,
    const float* __restrict__ wv, const float* __restrict__ x,
    unsigned short* __restrict__ Wp, unsigned short* __restrict__ Xp,
    float* __restrict__ sums)
{
  int t = blockIdx.x * 256 + threadIdx.x;      // 486*256 = 124416 = 1944 groups
  if (t < 768) sums[t] = 0.f;                  // zero q/k row-sum accumulators
  int lane = t & 63;
  int g = t >> 6;
  int quad = lane >> 4, col = lane & 15;
  union { int4 v; unsigned short u[8]; } o;
  if (g < 216) {                               // W: 36*6 groups
    int mt = g / 6, kc = g % 6;
    int oo = mt * 16 + col;
    int c0 = kc * 32 + quad * 8;
    const float* w = (oo < 192) ? (wq + (size_t)oo * 192)
                   : (oo < 384) ? (wk + (size_t)(oo - 192) * 192)
                                : (wv + (size_t)(oo - 384) * 192);
#pragma unroll
    for (int jj = 0; jj < 8; ++jj) o.u[jj] = f2bf(w[c0 + jj]);
    ((int4*)Wp)[(size_t)g * 64 + lane] = o.v;
  } else {                                     // X: 2*144*6 groups
    int gx = g - 216;
    int kc = gx % 6;
    int bnt = gx / 6;                          // b*144 + nt
    int b = bnt / 144;
    int n = (bnt % 144) * 16 + col;
    int c0 = kc * 32 + quad * 8;
    const float* xp = x + ((size_t)b * 192 + c0) * NSP + n;
#pragma unroll
    for (int jj = 0; jj < 8; ++jj) o.u[jj] = f2bf(xp[(size_t)jj * NSP]);
    ((int4*)Xp)[(size_t)gx * 64 + lane] = o.v;
  }
}

// ---------------------------------------------------------------------------
// Kernel 2: MFMA projection GEMM, fused everything.
//   Block = 32 o-rows (band) x 256 n-cols, 4 waves (each 32x64 via 2 mtiles).
//   Bands y: 0-5 = q head y, 6-11 = k head y-6, 12-17 = v rows (y-12)*32.
//   q/k: NO f32 round-trip -- raw values go straight to bf16 fragment layout
//        (Qp/Kp) via an LDS transpose, plus fused per-row sum-of-squares
//        atomics. Normalization itself is deferred into attn (the per-channel
//        scale product invq[c]*invk[c] folds into the K operand there).
//   v:   f32 direct to d_out region (as before).
// ---------------------------------------------------------------------------
__global__ __launch_bounds__(256) void proj_mfma(
    const bf16x8* __restrict__ Wp, const bf16x8* __restrict__ Xp,
    unsigned short* __restrict__ Qp, unsigned short* __restrict__ Kp,
    float* __restrict__ vout, float* __restrict__ sums)
{
  int lane = threadIdx.x & 63, w = threadIdx.x >> 6;
  int xblk = blockIdx.x;                       // 0..8 (256-col bands)
  int y    = blockIdx.y;                       // 0..17 (32-row bands)
  int b    = blockIdx.z;                       // 0..1
  int nt0  = xblk * 16 + w * 4;                // wave's 4 n-tiles
  int mt0  = y * 2;                            // two 16-row mtiles
  float4v acc[2][4];
#pragma unroll
  for (int t = 0; t < 2; ++t)
#pragma unroll
    for (int tt = 0; tt < 4; ++tt) acc[t][tt] = float4v{0.f,0.f,0.f,0.f};
#pragma unroll
  for (int kc = 0; kc < 6; ++kc) {
    bf16x8 a0 = Wp[(size_t)(mt0 * 6 + kc) * 64 + lane];
    bf16x8 a1 = Wp[(size_t)((mt0 + 1) * 6 + kc) * 64 + lane];
    const bf16x8* xb = Xp + (size_t)((b * 144 + nt0) * 6 + kc) * 64 + lane;
#pragma unroll
    for (int tt = 0; tt < 4; ++tt) {
      bf16x8 bfr = xb[(size_t)tt * 384];
      acc[0][tt] = __builtin_amdgcn_mfma_f32_16x16x32_bf16(a0, bfr, acc[0][tt], 0, 0, 0);
      acc[1][tt] = __builtin_amdgcn_mfma_f32_16x16x32_bf16(a1, bfr, acc[1][tt], 0, 0, 0);
    }
  }
  int quad = lane >> 4, col = lane & 15;

  if (y >= 12) {                               // v: direct f32 store
    float* dst = vout + ((size_t)b * 192 + (y - 12) * 32) * NSP;
#pragma unroll
    for (int t = 0; t < 2; ++t)
#pragma unroll
      for (int tt = 0; tt < 4; ++tt)
#pragma unroll
        for (int r = 0; r < 4; ++r)
          dst[(size_t)(t * 16 + quad * 4 + r) * NSP + (nt0 + tt) * 16 + col] = acc[t][tt][r];
    return;
  }

  // q/k band: fused row sum-of-squares (norm axis is n)
  int isK = (y >= 6) ? 1 : 0;
  int h = isK ? (y - 6) : y;
  int sbase = isK * 384 + b * 192 + h * 32;
#pragma unroll
  for (int t = 0; t < 2; ++t)
#pragma unroll
    for (int r = 0; r < 4; ++r) {
      float p = acc[t][0][r] * acc[t][0][r] + acc[t][1][r] * acc[t][1][r]
              + acc[t][2][r] * acc[t][2][r] + acc[t][3][r] * acc[t][3][r];
#pragma unroll
      for (int off = 1; off < 16; off <<= 1) p += __shfl_xor(p, off);
      if (col == 0) atomicAdd(&sums[sbase + t * 16 + quad * 4 + r], p);
    }

  // LDS transpose: [32 ch rows][256 n cols], pad 257 (reads 2-way, free)
  __shared__ float xs[32][257];
#pragma unroll
  for (int t = 0; t < 2; ++t)
#pragma unroll
    for (int tt = 0; tt < 4; ++tt)
#pragma unroll
      for (int r = 0; r < 4; ++r)
        xs[t * 16 + quad * 4 + r][(w * 4 + tt) * 16 + col] = acc[t][tt][r];
  __syncthreads();

  // fragment pack: thread covers jt-local = w+4i, its own lane slot
  unsigned short* Pp = isK ? Kp : Qp;
  int bh = b * 6 + h;
#pragma unroll
  for (int i = 0; i < 4; ++i) {
    int jtl = w + 4 * i;
    union { int4 v; unsigned short u[8]; } o;
#pragma unroll
    for (int jj = 0; jj < 8; ++jj) o.u[jj] = f2bf(xs[quad * 8 + jj][jtl * 16 + col]);
    ((int4*)Pp)[(size_t)(bh * 144 + xblk * 16 + jtl) * 64 + lane] = o.v;
  }
}

// ---------------------------------------------------------------------------
// Kernel 3: attention. Block = one (bh, itile=16 n-rows), 512 threads = 8
// waves. Wave w owns jt = w + 8u (u=0..17), interleaved so consecutive u
// across the 8 waves tile 256 contiguous output columns.
//
// Qp/Kp hold RAW projections; the l2-norm scales fold into the K operand:
//   S[n,m] = sum_c q[c,m] k[c,n] * (invq[c]*invk[c])  -> scale kf elem-wise
// by g[ch] once per block (8 unpack-mul-pack ops, amortized over 144 MFMAs).
//
// acc = mfma(qf, kf): lane(quad,col) reg r holds
//     S[n = itile*16 + col][m = jt*16 + quad*4 + r]
// exp(S*T) cached as packed bf16 in registers; pass 2 goes through an LDS
// transpose so every global store is a contiguous 128B-aligned 1KB wave store.
// ---------------------------------------------------------------------------
__global__ __launch_bounds__(512) void attn_kernel(
    const bf16x8* __restrict__ Qp, const bf16x8* __restrict__ Kp,
    const float* __restrict__ sums, const float* __restrict__ temp,
    float* __restrict__ out)
{
  int lane = threadIdx.x & 63, w = threadIdx.x >> 6;   // 8 waves
  int itile = blockIdx.x;                      // 0..143
  int bh = blockIdx.y;                         // 0..11
  int quad = lane >> 4, col = lane & 15;
  float T = temp[bh % 6];

  // per-channel combined norm scale g[ch] = invq[ch]*invk[ch]
  __shared__ float gs[32];
  if (threadIdx.x < 32) {
    int bq = bh / 6, hq = bh % 6;
    float sq = sums[bq * 192 + hq * 32 + threadIdx.x];
    float sk = sums[384 + bq * 192 + hq * 32 + threadIdx.x];
    gs[threadIdx.x] = (1.0f / fmaxf(sqrtf(sq), 1e-12f))
                    * (1.0f / fmaxf(sqrtf(sk), 1e-12f));
  }
  __syncthreads();

  // K tile for this block's 16 n-rows, scaled by g (B-frag: elem jj <-> ch)
  union { bf16x8 v; unsigned short u[8]; } kr, ks;
  kr.v = Kp[((size_t)bh * NT + itile) * 64 + lane];
#pragma unroll
  for (int jj = 0; jj < 8; ++jj)
    ks.u[jj] = f2bf(bf2f(kr.u[jj]) * gs[quad * 8 + jj]);
  bf16x8 kf = ks.v;
  const bf16x8* qb = Qp + (size_t)bh * NT * 64 + lane;

  unsigned int ec[36];                         // 18 jt x 4 exps packed bf16
  float s = 0.f;
#pragma unroll
  for (int u = 0; u < 18; ++u) {
    int jt = w + 8 * u;                        // interleaved assignment
    bf16x8 qf = qb[(size_t)jt * 64];
    float4v acc = {0.f,0.f,0.f,0.f};
    acc = __builtin_amdgcn_mfma_f32_16x16x32_bf16(qf, kf, acc, 0, 0, 0);
    float e0 = __expf(acc[0] * T);
    float e1 = __expf(acc[1] * T);
    float e2 = __expf(acc[2] * T);
    float e3 = __expf(acc[3] * T);
    s += (e0 + e1) + (e2 + e3);
    ec[2*u]   = (unsigned int)f2bf(e0) | ((unsigned int)f2bf(e1) << 16);
    ec[2*u+1] = (unsigned int)f2bf(e2) | ((unsigned int)f2bf(e3) << 16);
  }
  // reduce across the 4 quads (lanes col, col+16, col+32, col+48):
  s += __shfl_xor(s, 16);
  s += __shfl_xor(s, 32);
  __shared__ float ls[8][16];
  if (lane < 16) ls[w][lane] = s;
  __syncthreads();
  float tot = 0.f;
#pragma unroll
  for (int ww = 0; ww < 8; ++ww) tot += ls[ww][col];
  float inv = 1.0f / tot;

  // pass 2: 9 chunks of 256 columns. Scale 8 vals/thread into a padded LDS
  // tile, then each wave streams 2 complete rows as contiguous 1KB stores.
  __shared__ float xs[16][260];                // 16.6 KB, +4 pad, 16B aligned
  float* obase = out + (size_t)bh * NSP * NSP + (size_t)(itile * 16) * NSP;
  for (int c = 0; c < 9; ++c) {
#pragma unroll
    for (int ul = 0; ul < 2; ++ul) {
      int u = 2 * c + ul;                      // jt = w + 8u -> chunk-local col
      unsigned int p0 = ec[2*u], p1 = ec[2*u+1];
      float4v o4;
      o4[0] = bf2f(p0 & 0xffffu) * inv;
      o4[1] = bf2f(p0 >> 16)     * inv;
      o4[2] = bf2f(p1 & 0xffffu) * inv;
      o4[3] = bf2f(p1 >> 16)     * inv;
      *(float4v*)&xs[col][(ul * 8 + w) * 16 + quad * 4] = o4;
    }
    __syncthreads();
#pragma unroll
    for (int rr = 0; rr < 2; ++rr) {
      int row = w + rr * 8;
      float4v o4 = *(const float4v*)&xs[row][lane * 4];
      *(float4v*)(obase + (size_t)row * NSP + c * 256 + lane * 4) = o4;
    }
    __syncthreads();
  }
}

extern "C" void kernel_launch(void* const* d_in, const int* in_sizes, int n_in,
                              void* d_out, int out_size, void* d_ws, size_t ws_size,
                              hipStream_t stream) {
  const float* x    = (const float*)d_in[0];   // [2][192][2304]
  const float* wq   = (const float*)d_in[1];   // [192][192]
  const float* wk   = (const float*)d_in[2];
  const float* wv   = (const float*)d_in[3];
  const float* temp = (const float*)d_in[4];   // [6]

  float* attn_out = (float*)d_out;                     // [2][6][2304][2304]
  float* vout     = attn_out + (size_t)ATTN_ELEMS;     // [2][6][32][2304]

  // workspace carve-up (~5.6 MB total, all 16B-aligned)
  float* sums = (float*)d_ws;                          // 768 f32 (atomics)
  unsigned short* Wp = (unsigned short*)(sums + 768);  // 110592 bf16
  unsigned short* Xp = Wp + 110592;                    // 884736 bf16
  unsigned short* Qp = Xp + 884736;                    // 884736 bf16
  unsigned short* Kp = Qp + 884736;                    // 884736 bf16

  hipLaunchKernelGGL(prep_pack, dim3(486), dim3(256), 0, stream,
                     wq, wk, wv, x, Wp, Xp, sums);
  hipLaunchKernelGGL(proj_mfma, dim3(9, 18, 2), dim3(256), 0, stream,
                     (const bf16x8*)Wp, (const bf16x8*)Xp, Qp, Kp, vout, sums);
  hipLaunchKernelGGL(attn_kernel, dim3(144, 12), dim3(512), 0, stream,
                     (const bf16x8*)Qp, (const bf16x8*)Kp, sums, temp, attn_out);
}